// Round 15
// baseline (491.359 us; speedup 1.0000x reference)
//
#include <hip/hip_runtime.h>

using u16 = unsigned short;
using bf16x8 = __attribute__((ext_vector_type(8))) short;
using f32x4  = __attribute__((ext_vector_type(4))) float;

#define DIM   1024
#define HW    3840
#define NSEL  4224
#define NK    8224
#define NKPAD 8320
#define NH    16
#define KVB   64
#define THR   50.0f

typedef __attribute__((address_space(1))) const unsigned GU;
typedef __attribute__((address_space(3))) unsigned LU;

__device__ __forceinline__ u16 f2bf(float x) {
    unsigned u = __float_as_uint(x);
    return (u16)((u + 0x7FFFu + ((u >> 16) & 1u)) >> 16);
}

__device__ __forceinline__ float exp2fast(float x) {
    return __builtin_amdgcn_exp2f(x);
}

// ---------- fused prep ----------
// [0,4096)      transpose_w
// [4096,7936)   build_qin
// [7936,8112)   sel-gather: 176 blocks = 11 frames x 16 d-chunks; wave owns 16 d;
//               d-outer / 64-idx-batch-inner -> same-d lines L1-resident (2x fewer fetches);
//               per-lane register transpose (fully unrolled), 32B row writes.
// [8112,12208)  em / gc / zero-pad rows (row = b - 8112 + NSEL)
__global__ void prep_kernel(const float* __restrict__ Wq, const float* __restrict__ Wk,
                            const float* __restrict__ Wv, const float* __restrict__ Wo,
                            const float* __restrict__ fc, const float* __restrict__ ps,
                            const float* __restrict__ fr, const float* __restrict__ em,
                            const float* __restrict__ gc, const int* __restrict__ sel,
                            const int* __restrict__ midx, const int* __restrict__ gidx,
                            u16* __restrict__ WT, u16* __restrict__ qin, u16* __restrict__ kin) {
    const int b = blockIdx.x;
    const int tid = threadIdx.x;
    if (b < 4096) {
        const int zz = b >> 10, yy = (b >> 5) & 31, xx = b & 31;
        const float* src = zz == 0 ? Wq : zz == 1 ? Wk : zz == 2 ? Wv : Wo;
        u16* dst = WT + (size_t)zz * DIM * DIM;
        __shared__ float t[32][33];
        const int n0 = xx * 32, k0 = yy * 32;
        const int tx = tid & 31, ty = tid >> 5;
#pragma unroll
        for (int j = 0; j < 4; ++j)
            t[ty + 8 * j][tx] = src[(size_t)(k0 + ty + 8 * j) * DIM + n0 + tx];
        __syncthreads();
#pragma unroll
        for (int j = 0; j < 4; ++j)
            dst[(size_t)(n0 + ty + 8 * j) * DIM + k0 + tx] = f2bf(t[tx][ty + 8 * j]);
    } else if (b < 7936) {
        const int bb = b - 4096;
        const int xx = bb % 120, yy = bb / 120;
        __shared__ float t[32][33];
        const int p0 = xx * 32, d0 = yy * 32;
        const int tx = tid & 31, ty = tid >> 5;
#pragma unroll
        for (int j = 0; j < 4; ++j) {
            int d = d0 + ty + 8 * j;
            t[ty + 8 * j][tx] = fc[(size_t)d * HW + p0 + tx] + ps[(size_t)d * HW + p0 + tx];
        }
        __syncthreads();
#pragma unroll
        for (int j = 0; j < 4; ++j)
            qin[(size_t)(p0 + ty + 8 * j) * DIM + d0 + tx] = f2bf(t[tx][ty + 8 * j]);
    } else if (b < 8112) {
        // sel-gather block: f = frame, dc = d-chunk of 64
        const int fb = b - 7936;
        const int f = fb >> 4, dc = fb & 15;
        const int d0 = dc * 64;
        __shared__ int selS[384];
        selS[tid] = sel[f * 384 + tid];
        if (tid < 128) selS[256 + tid] = sel[f * 384 + 256 + tid];
        __syncthreads();
        const int w = tid >> 6, l = tid & 63;
        const int dbase = d0 + w * 16;                  // this wave's 16 d values
        const float* frF = fr + (size_t)f * DIM * HW;
        unsigned pk[6][8];                              // [j6][d-pair] packed 2x bf16
#pragma unroll
        for (int dr = 0; dr < 16; ++dr) {               // d OUTER: same-d batches consecutive
            const int d = dbase + dr;
            const float* frD = frF + (size_t)d * HW;
            const float* psD = ps + (size_t)d * HW;
#pragma unroll
            for (int j6 = 0; j6 < 6; ++j6) {            // 6 batches x 64 idx (L1-resident lines)
                const int idx = selS[j6 * 64 + l];
                const float v = frD[idx] + psD[idx];
                const unsigned h = (unsigned)f2bf(v);
                if ((dr & 1) == 0) pk[j6][dr >> 1] = h;
                else               pk[j6][dr >> 1] |= h << 16;
            }
        }
#pragma unroll
        for (int j6 = 0; j6 < 6; ++j6) {
            const size_t row = (size_t)f * 384 + j6 * 64 + l;
            u16* dst = kin + row * DIM + dbase;
            uint4 a = {pk[j6][0], pk[j6][1], pk[j6][2], pk[j6][3]};
            uint4 c = {pk[j6][4], pk[j6][5], pk[j6][6], pk[j6][7]};
            *(uint4*)(dst) = a;
            *(uint4*)(dst + 8) = c;
        }
    } else {
        const int row = b - 8112 + NSEL;
        u16* dst = kin + (size_t)row * DIM;
        const int t = tid;
        if (row < NSEL + 2000) {
            const float* src = em + (size_t)midx[row - NSEL] * DIM;
#pragma unroll
            for (int j = 0; j < 4; ++j) { int d = t + 256 * j; dst[d] = f2bf(src[d]); }
        } else if (row < NK) {
            const float* src = gc + (size_t)gidx[row - (NSEL + 2000)] * DIM;
#pragma unroll
            for (int j = 0; j < 4; ++j) { int d = t + 256 * j; dst[d] = f2bf(src[d]); }
        } else {
#pragma unroll
            for (int j = 0; j < 4; ++j) dst[t + 256 * j] = 0;
        }
    }
}

// ---------- GEMM body: m97 schedule — single-buffer 32KB LDS, global_load_lds w16 ----------
__device__ __forceinline__ void gemm_bt_body(const u16* __restrict__ A,
                                             const u16* __restrict__ B,
                                             void* __restrict__ Cout,
                                             const float* __restrict__ r1,
                                             const float* __restrict__ r2,
                                             int ldc, int mode, float scale,
                                             int bx, int by) {
    __shared__ __align__(16) u16 As[128 * 64];
    __shared__ __align__(16) u16 Bs[128 * 64];
    const int tid = threadIdx.x;
    const int l = tid & 63;
    const int wv = tid >> 6;
    const int wr = (wv >> 1) * 64, wc = (wv & 1) * 64;
    const int g = l >> 4, lo = l & 15;
    const size_t bm = (size_t)by * 128, bn = (size_t)bx * 128;
    const f32x4 fzero = {0.f, 0.f, 0.f, 0.f};

    f32x4 acc[4][4];
#pragma unroll
    for (int i = 0; i < 4; ++i)
#pragma unroll
        for (int j = 0; j < 4; ++j) acc[i][j] = fzero;

#define GSTAGE(KT)                                                                              \
    {                                                                                           \
        const int k0_ = (KT) * 64;                                                              \
        _Pragma("unroll") for (int q = 0; q < 4; ++q) {                                         \
            const int idx = q * 256 + tid;                                                      \
            const int row = idx >> 3, c8 = idx & 7;                                             \
            const int scol = (c8 ^ (row & 7)) * 8;                                              \
            const int dbase = q * 2048 + wv * 512;                                              \
            __builtin_amdgcn_global_load_lds((GU*)(A + (bm + row) * DIM + k0_ + scol),          \
                                             (LU*)&As[dbase], 16, 0, 0);                        \
            __builtin_amdgcn_global_load_lds((GU*)(B + (bn + row) * DIM + k0_ + scol),          \
                                             (LU*)&Bs[dbase], 16, 0, 0);                        \
        }                                                                                       \
    }

#define GCOMPUTE()                                                                              \
    {                                                                                           \
        _Pragma("unroll") for (int ks = 0; ks < 2; ++ks) {                                      \
            bf16x8 af[4], bfv[4];                                                               \
            _Pragma("unroll") for (int mi = 0; mi < 4; ++mi) {                                  \
                const int row = wr + mi * 16 + lo;                                              \
                const int sw = (ks * 4 + g) ^ (row & 7);                                        \
                af[mi] = *(const bf16x8*)(&As[row * 64 + sw * 8]);                              \
            }                                                                                   \
            _Pragma("unroll") for (int ni = 0; ni < 4; ++ni) {                                  \
                const int row = wc + ni * 16 + lo;                                              \
                const int sw = (ks * 4 + g) ^ (row & 7);                                        \
                bfv[ni] = *(const bf16x8*)(&Bs[row * 64 + sw * 8]);                             \
            }                                                                                   \
            _Pragma("unroll") for (int mi = 0; mi < 4; ++mi)                                    \
                _Pragma("unroll") for (int ni = 0; ni < 4; ++ni)                                \
                    acc[mi][ni] = __builtin_amdgcn_mfma_f32_16x16x32_bf16(af[mi], bfv[ni], acc[mi][ni], 0, 0, 0); \
        }                                                                                       \
    }

#pragma unroll 1
    for (int kt = 0; kt < 16; ++kt) {
        GSTAGE(kt)
        asm volatile("s_waitcnt vmcnt(0)" ::: "memory");
        __syncthreads();
        GCOMPUTE()
        __syncthreads();
    }
#undef GCOMPUTE
#undef GSTAGE

    if (mode == 0) {
        u16* C = (u16*)Cout;
#pragma unroll
        for (int mi = 0; mi < 4; ++mi)
#pragma unroll
            for (int ni = 0; ni < 4; ++ni)
#pragma unroll
                for (int r = 0; r < 4; ++r) {
                    size_t m = bm + wr + mi * 16 + g * 4 + r;
                    size_t n = bn + wc + ni * 16 + lo;
                    C[m * (size_t)ldc + n] = f2bf(acc[mi][ni][r] * scale);
                }
    } else if (mode == 2) {
        u16* C = (u16*)Cout;
#pragma unroll
        for (int mi = 0; mi < 4; ++mi)
#pragma unroll
            for (int ni = 0; ni < 4; ++ni)
#pragma unroll
                for (int r = 0; r < 4; ++r) {
                    size_t m = bm + wr + mi * 16 + g * 4 + r;
                    size_t n = bn + wc + ni * 16 + lo;
                    size_t o = (n >> 6) * ((size_t)NKPAD * 64) + m * 64 + (n & 63);
                    C[o] = f2bf(acc[mi][ni][r] * scale);
                }
    } else {
        float* C = (float*)Cout;
#pragma unroll
        for (int mi = 0; mi < 4; ++mi)
#pragma unroll
            for (int ni = 0; ni < 4; ++ni)
#pragma unroll
                for (int r = 0; r < 4; ++r) {
                    size_t m = bm + wr + mi * 16 + g * 4 + r;
                    size_t n = bn + wc + ni * 16 + lo;
                    size_t o = m * (size_t)ldc + n;
                    C[o] = acc[mi][ni][r] + r1[o] + r2[o];
                }
    }
}

// ---------- fused Q/K/V projections: [0,240) Q | [240,760) K | [760,1280) V ----------
__global__ __launch_bounds__(256, 3) void proj_kernel(const u16* __restrict__ qin,
                                                      const u16* __restrict__ kin,
                                                      const u16* __restrict__ WT,
                                                      u16* __restrict__ Qp,
                                                      u16* __restrict__ Kp,
                                                      u16* __restrict__ Vt) {
    const int b = blockIdx.x;
    if (b < 240) {
        gemm_bt_body(qin, WT, Qp, nullptr, nullptr, 1024, 0, 0.18033688f, b % 8, b / 8);
    } else if (b < 760) {
        const int bb = b - 240;
        gemm_bt_body(kin, WT + 1048576, Kp, nullptr, nullptr, 1024, 2, 1.0f, bb % 8, bb / 8);
    } else {
        const int bb = b - 760;
        gemm_bt_body(WT + 2097152, kin, Vt, nullptr, nullptr, NKPAD, 0, 1.0f, bb % 65, bb / 65);
    }
}

// ---------- out-projection ----------
__global__ __launch_bounds__(256, 3) void outproj_kernel(const u16* __restrict__ WTo,
                                                         const u16* __restrict__ ctx,
                                                         float* __restrict__ out,
                                                         const float* __restrict__ fc,
                                                         const float* __restrict__ ps) {
    gemm_bt_body(WTo, ctx, out, fc, ps, HW, 1, 1.0f, blockIdx.x, blockIdx.y);
}

// ---------- flash attention: 4 waves x 32 q-rows, LDS-shared K/V (KVB=64), dbuf ----------
// R10 version verbatim (measured 188-189 us, passed, 0 conflicts). Grid (NH, 30).
__global__ __launch_bounds__(256, 3) void attn_kernel(const u16* __restrict__ Q,
                                                      const u16* __restrict__ Kh,
                                                      const u16* __restrict__ Vt,
                                                      u16* __restrict__ ctx) {
    __shared__ __align__(16) u16 Kl[2][4096];
    __shared__ __align__(16) u16 Vl[2][4096];
    __shared__ float invl_s[4][32];
    const int h = blockIdx.x;                 // bid%8 = h%8 -> 2 heads per XCD L2
    const int tid = threadIdx.x;
    const int l = tid & 63, wv = tid >> 6;
    const int g = l >> 4, lo = l & 15;
    const int hoff = h * 64;
    const int qw = blockIdx.y * 128 + wv * 32;
    const f32x4 fzero = {0.f, 0.f, 0.f, 0.f};
    const int sig = (lo >> 2) * 8 + (lo & 3);

    const u16* Ksrc = Kh + (size_t)h * NKPAD * 64;
    const u16* Vsrc = Vt + (size_t)hoff * NKPAD;

    bf16x8 qa[2][2];
#pragma unroll
    for (int mi = 0; mi < 2; ++mi)
#pragma unroll
        for (int ks = 0; ks < 2; ++ks)
            qa[mi][ks] = *(const bf16x8*)(Q + (size_t)(qw + mi * 16 + lo) * DIM + hoff + ks * 32 + g * 8);

    f32x4 acc[2][4];
#pragma unroll
    for (int mi = 0; mi < 2; ++mi)
#pragma unroll
        for (int ni = 0; ni < 4; ++ni) acc[mi][ni] = fzero;
    float mrow[2] = {-1e30f, -1e30f};
    float lsum[2] = {0.f, 0.f};
    float pmax[2] = {-1e30f, -1e30f};

#define STAGE(BUF, IT)                                                                          \
    {                                                                                           \
        const int kks = (IT) * KVB;                                                             \
        _Pragma("unroll") for (int j = 0; j < 2; ++j) {                                         \
            const int inst = wv * 2 + j;                                                        \
            const int r_ = inst * 8 + (l >> 3);                                                 \
            const int c_ = l & 7;                                                               \
            const int hk_ = ((l >> 3) & 3) | ((inst & 1) << 2);                                 \
            const u16* gK = Ksrc + (size_t)(kks + r_) * 64 + ((c_ ^ hk_) * 8);                  \
            __builtin_amdgcn_global_load_lds((GU*)gK, (LU*)&Kl[BUF][inst * 512], 16, 0, 0);     \
            const u16* gV = Vsrc + (size_t)r_ * NKPAD + kks + ((c_ ^ (r_ & 7)) * 8);            \
            __builtin_amdgcn_global_load_lds((GU*)gV, (LU*)&Vl[BUF][inst * 512], 16, 0, 0);     \
        }                                                                                       \
    }

#define COMPUTE(BUF, NT, NS)                                                                    \
    {                                                                                           \
        f32x4 S[2][4];                                                                          \
        _Pragma("unroll") for (int kp = 0; kp < (NT) / 2; ++kp) {                               \
            bf16x8 kf[2][2];                                                                    \
            _Pragma("unroll") for (int k2 = 0; k2 < 2; ++k2)                                    \
                _Pragma("unroll") for (int ks = 0; ks < 2; ++ks) {                              \
                    const int kt = kp * 2 + k2;                                                 \
                    const int row = (kt >> 1) * 32 + (kt & 1) * 4 + sig;                        \
                    const int hk_ = (row & 3) | (((row >> 3) & 1) << 2);                        \
                    const int ck = (ks * 4 + g) ^ hk_;                                          \
                    kf[k2][ks] = *(const bf16x8*)(&Kl[BUF][row * 64 + ck * 8]);                 \
                }                                                                               \
            _Pragma("unroll") for (int mi = 0; mi < 2; ++mi)                                    \
                _Pragma("unroll") for (int k2 = 0; k2 < 2; ++k2) {                              \
                    f32x4 s_ = __builtin_amdgcn_mfma_f32_16x16x32_bf16(kf[k2][0], qa[mi][0], fzero, 0, 0, 0); \
                    S[mi][kp * 2 + k2] = __builtin_amdgcn_mfma_f32_16x16x32_bf16(kf[k2][1], qa[mi][1], s_, 0, 0, 0); \
                }                                                                               \
        }                                                                                       \
        _Pragma("unroll") for (int mi = 0; mi < 2; ++mi)                                        \
            _Pragma("unroll") for (int kt = 0; kt < (NT); ++kt) {                               \
                f32x4 sv = S[mi][kt];                                                           \
                pmax[mi] = fmaxf(pmax[mi], fmaxf(fmaxf(sv[0], sv[1]), fmaxf(sv[2], sv[3])));    \
            }                                                                                   \
        if (__any(fmaxf(pmax[0] - mrow[0], pmax[1] - mrow[1]) > THR)) {                         \
            _Pragma("unroll") for (int mi = 0; mi < 2; ++mi) {                                  \
                float v = pmax[mi];                                                             \
                v = fmaxf(v, __shfl_xor(v, 16));                                                \
                v = fmaxf(v, __shfl_xor(v, 32));                                                \
                float mn = fmaxf(mrow[mi], v);                                                  \
                float fct = exp2fast(mrow[mi] - mn);                                            \
                mrow[mi] = mn;                                                                  \
                lsum[mi] *= fct;                                                                \
                _Pragma("unroll") for (int r = 0; r < 4; ++r) {                                 \
                    float fr_ = __shfl(fct, g * 4 + r);                                         \
                    _Pragma("unroll") for (int ni = 0; ni < 4; ++ni) acc[mi][ni][r] *= fr_;     \
                }                                                                               \
            }                                                                                   \
        }                                                                                       \
        _Pragma("unroll") for (int s = 0; s < (NS); ++s) {                                      \
            bf16x8 vb[4];                                                                       \
            _Pragma("unroll") for (int ni = 0; ni < 4; ++ni) {                                  \
                const int row = ni * 16 + lo;                                                   \
                const int ck = (s * 4 + g) ^ (row & 7);                                         \
                vb[ni] = *(const bf16x8*)(&Vl[BUF][row * 64 + ck * 8]);                         \
            }                                                                                   \
            _Pragma("unroll") for (int mi = 0; mi < 2; ++mi) {                                  \
                float p0 = exp2fast(S[mi][2 * s][0] - mrow[mi]);                                \
                float p1 = exp2fast(S[mi][2 * s][1] - mrow[mi]);                                \
                float p2 = exp2fast(S[mi][2 * s][2] - mrow[mi]);                                \
                float p3 = exp2fast(S[mi][2 * s][3] - mrow[mi]);                                \
                float p4 = exp2fast(S[mi][2 * s + 1][0] - mrow[mi]);                            \
                float p5 = exp2fast(S[mi][2 * s + 1][1] - mrow[mi]);                            \
                float p6 = exp2fast(S[mi][2 * s + 1][2] - mrow[mi]);                            \
                float p7 = exp2fast(S[mi][2 * s + 1][3] - mrow[mi]);                            \
                lsum[mi] += ((p0 + p1) + (p2 + p3)) + ((p4 + p5) + (p6 + p7));                  \
                union { unsigned u[4]; bf16x8 v; } pu;                                          \
                asm("v_cvt_pk_bf16_f32 %0, %1, %2" : "=v"(pu.u[0]) : "v"(p0), "v"(p1));         \
                asm("v_cvt_pk_bf16_f32 %0, %1, %2" : "=v"(pu.u[1]) : "v"(p2), "v"(p3));         \
                asm("v_cvt_pk_bf16_f32 %0, %1, %2" : "=v"(pu.u[2]) : "v"(p4), "v"(p5));         \
                asm("v_cvt_pk_bf16_f32 %0, %1, %2" : "=v"(pu.u[3]) : "v"(p6), "v"(p7));         \
                _Pragma("unroll") for (int ni = 0; ni < 4; ++ni)                                \
                    acc[mi][ni] = __builtin_amdgcn_mfma_f32_16x16x32_bf16(pu.v, vb[ni], acc[mi][ni], 0, 0, 0); \
            }                                                                                   \
        }                                                                                       \
    }

    STAGE(0, 0)
    asm volatile("s_waitcnt vmcnt(0)" ::: "memory");
    __syncthreads();

#pragma unroll 1
    for (int it = 0; it < 128; it += 2) {
        STAGE(1, it + 1)
        COMPUTE(0, 4, 2)
        asm volatile("s_waitcnt vmcnt(0)" ::: "memory");
        __syncthreads();
        STAGE(0, it + 2)          // it=126 stages the tail window (keys 8192..8255)
        COMPUTE(1, 4, 2)
        asm volatile("s_waitcnt vmcnt(0)" ::: "memory");
        __syncthreads();
    }
    // tail: keys 8192..8223 (32 real keys; zero-padded rows never touched)
    COMPUTE(0, 2, 1)
#undef COMPUTE
#undef STAGE

    // row totals: sum l partials across the 4 g-lanes of each q-row
#pragma unroll
    for (int mi = 0; mi < 2; ++mi) {
        float t = lsum[mi];
        t += __shfl_xor(t, 16);
        t += __shfl_xor(t, 32);
        lsum[mi] = t;
    }
    // broadcast 1/l through per-wave LDS (acc rows are g*4+r, state rows are lo)
    if (l < 16) {
        invl_s[wv][lo] = 1.0f / lsum[0];
        invl_s[wv][16 + lo] = 1.0f / lsum[1];
    }
#pragma unroll
    for (int mi = 0; mi < 2; ++mi)
#pragma unroll
        for (int ni = 0; ni < 4; ++ni)
#pragma unroll
            for (int r = 0; r < 4; ++r) {
                float val = acc[mi][ni][r] * invl_s[wv][mi * 16 + g * 4 + r];
                ctx[(size_t)(qw + mi * 16 + g * 4 + r) * DIM + hoff + ni * 16 + lo] = f2bf(val);
            }
}

extern "C" void kernel_launch(void* const* d_in, const int* in_sizes, int n_in,
                              void* d_out, int out_size, void* d_ws, size_t ws_size,
                              hipStream_t stream) {
    const float* fc  = (const float*)d_in[0];
    const float* ps  = (const float*)d_in[1];
    const float* fr  = (const float*)d_in[2];
    const float* em  = (const float*)d_in[3];
    const float* gc  = (const float*)d_in[4];
    const float* Wq  = (const float*)d_in[5];
    const float* Wk  = (const float*)d_in[6];
    const float* Wv  = (const float*)d_in[7];
    const float* Wo  = (const float*)d_in[8];
    const int* sel   = (const int*)d_in[9];
    const int* midx  = (const int*)d_in[10];
    const int* gidx  = (const int*)d_in[11];

    char* w = (char*)d_ws;
    u16* WT  = (u16*)(w);                       //  8 MB: 4x [1024][1024] bf16
    u16* qin = (u16*)(w + 8388608ull);          //  7.5 MB [3840][1024]
    u16* kin = (u16*)(w + 16252928ull);         // 16.25 MB [8320][1024]
    u16* Qp  = (u16*)(w + 33292288ull);         //  7.5 MB [3840][1024]
    u16* Kp  = (u16*)(w + 41156608ull);         // 16.25 MB [16][8320][64] head-major
    u16* Vt  = (u16*)(w + 58195968ull);         // 16.25 MB [1024][8320]
    u16* ctx = (u16*)(w + 75235328ull);         //  7.5 MB [3840][1024]
    float* out = (float*)d_out;

    prep_kernel<<<dim3(12208), dim3(256), 0, stream>>>(Wq, Wk, Wv, Wo, fc, ps, fr, em, gc,
                                                       sel, midx, gidx, WT, qin, kin);
    proj_kernel<<<dim3(1280), dim3(256), 0, stream>>>(qin, kin, WT, Qp, Kp, Vt);

    attn_kernel<<<dim3(NH, 30), dim3(256), 0, stream>>>(Qp, Kp, Vt, ctx);

    outproj_kernel<<<dim3(30, 8), dim3(256), 0, stream>>>(WT + 3145728, ctx, out, fc, ps);
}

// Round 16
// 342.441 us; speedup vs baseline: 1.4349x; 1.4349x over previous
//
#include <hip/hip_runtime.h>

using u16 = unsigned short;
using bf16x8 = __attribute__((ext_vector_type(8))) short;
using f32x4  = __attribute__((ext_vector_type(4))) float;

#define DIM   1024
#define HW    3840
#define NSEL  4224
#define NK    8224
#define NKPAD 8320
#define NH    16
#define KVB   64
#define THR   50.0f

typedef __attribute__((address_space(1))) const unsigned GU;
typedef __attribute__((address_space(3))) unsigned LU;

__device__ __forceinline__ u16 f2bf(float x) {
    unsigned u = __float_as_uint(x);
    return (u16)((u + 0x7FFFu + ((u >> 16) & 1u)) >> 16);
}

__device__ __forceinline__ float exp2fast(float x) {
    return __builtin_amdgcn_exp2f(x);
}

// ---------- fused prep ----------
// [0,4096)       transpose_w
// [4096,7936)    build_qin
// [7936,8266)    sel STREAMING scatter: 330 blocks = 11 frames x 30 hw-tiles (128 px).
//                Read fr+ps tile [64 d][128 px] fully coalesced into LDS; scatter the
//                ~13 selected columns to kin rows (64 contiguous d per wave-write).
// [8266,12362)   em / gc / zero-pad rows (row = b - 8266 + NSEL)
__global__ void prep_kernel(const float* __restrict__ Wq, const float* __restrict__ Wk,
                            const float* __restrict__ Wv, const float* __restrict__ Wo,
                            const float* __restrict__ fc, const float* __restrict__ ps,
                            const float* __restrict__ fr, const float* __restrict__ em,
                            const float* __restrict__ gc, const int* __restrict__ sel,
                            const int* __restrict__ midx, const int* __restrict__ gidx,
                            u16* __restrict__ WT, u16* __restrict__ qin, u16* __restrict__ kin) {
    const int b = blockIdx.x;
    const int tid = threadIdx.x;
    if (b < 4096) {
        const int zz = b >> 10, yy = (b >> 5) & 31, xx = b & 31;
        const float* src = zz == 0 ? Wq : zz == 1 ? Wk : zz == 2 ? Wv : Wo;
        u16* dst = WT + (size_t)zz * DIM * DIM;
        __shared__ float t[32][33];
        const int n0 = xx * 32, k0 = yy * 32;
        const int tx = tid & 31, ty = tid >> 5;
#pragma unroll
        for (int j = 0; j < 4; ++j)
            t[ty + 8 * j][tx] = src[(size_t)(k0 + ty + 8 * j) * DIM + n0 + tx];
        __syncthreads();
#pragma unroll
        for (int j = 0; j < 4; ++j)
            dst[(size_t)(n0 + ty + 8 * j) * DIM + k0 + tx] = f2bf(t[tx][ty + 8 * j]);
    } else if (b < 7936) {
        const int bb = b - 4096;
        const int xx = bb % 120, yy = bb / 120;
        __shared__ float t[32][33];
        const int p0 = xx * 32, d0 = yy * 32;
        const int tx = tid & 31, ty = tid >> 5;
#pragma unroll
        for (int j = 0; j < 4; ++j) {
            int d = d0 + ty + 8 * j;
            t[ty + 8 * j][tx] = fc[(size_t)d * HW + p0 + tx] + ps[(size_t)d * HW + p0 + tx];
        }
        __syncthreads();
#pragma unroll
        for (int j = 0; j < 4; ++j)
            qin[(size_t)(p0 + ty + 8 * j) * DIM + d0 + tx] = f2bf(t[tx][ty + 8 * j]);
    } else if (b < 8266) {
        // streaming sel scatter: f = frame, t = hw-tile of 128 px
        const int fb = b - 7936;
        const int f = fb / 30, tt = fb % 30;
        const int px0 = tt * 128;
        __shared__ float tile[64][129];          // pad 129: row-write ok, col-read 2-way (free)
        __shared__ int selS[384];
        __shared__ int hits[384];
        __shared__ int cnt;
        if (tid == 0) cnt = 0;
        selS[tid] = sel[f * 384 + tid];
        if (tid < 128) selS[256 + tid] = sel[f * 384 + 256 + tid];
        __syncthreads();
        for (int j = tid; j < 384; j += 256) {
            const int idx = selS[j];
            if (idx >= px0 && idx < px0 + 128) {
                const int pos = atomicAdd(&cnt, 1);
                hits[pos] = (j << 8) | (idx - px0);
            }
        }
        __syncthreads();
        const int nh = cnt;
        const int wv = tid >> 6, l = tid & 63;
        const float* frF = fr + (size_t)f * DIM * HW;
#pragma unroll 1
        for (int dc = 0; dc < 16; ++dc) {
            const int d0 = dc * 64;
            // coalesced tile load: 2048 float4 pairs across 256 threads
#pragma unroll
            for (int q = 0; q < 8; ++q) {
                const int e = q * 256 + tid;
                const int dd = e >> 5, pp = (e & 31) * 4;
                const float4 a = *(const float4*)(frF + (size_t)(d0 + dd) * HW + px0 + pp);
                const float4 c = *(const float4*)(ps + (size_t)(d0 + dd) * HW + px0 + pp);
                tile[dd][pp + 0] = a.x + c.x;
                tile[dd][pp + 1] = a.y + c.y;
                tile[dd][pp + 2] = a.z + c.z;
                tile[dd][pp + 3] = a.w + c.w;
            }
            __syncthreads();
            for (int hh = wv; hh < nh; hh += 4) {
                const int e2 = hits[hh];
                const int j = e2 >> 8, p = e2 & 255;
                kin[(size_t)(f * 384 + j) * DIM + d0 + l] = f2bf(tile[l][p]);
            }
            __syncthreads();
        }
    } else {
        const int row = b - 8266 + NSEL;
        u16* dst = kin + (size_t)row * DIM;
        const int t = tid;
        if (row < NSEL + 2000) {
            const float* src = em + (size_t)midx[row - NSEL] * DIM;
#pragma unroll
            for (int j = 0; j < 4; ++j) { int d = t + 256 * j; dst[d] = f2bf(src[d]); }
        } else if (row < NK) {
            const float* src = gc + (size_t)gidx[row - (NSEL + 2000)] * DIM;
#pragma unroll
            for (int j = 0; j < 4; ++j) { int d = t + 256 * j; dst[d] = f2bf(src[d]); }
        } else {
#pragma unroll
            for (int j = 0; j < 4; ++j) dst[t + 256 * j] = 0;
        }
    }
}

// ---------- GEMM body: m97 schedule — single-buffer 32KB LDS, global_load_lds w16 ----------
__device__ __forceinline__ void gemm_bt_body(const u16* __restrict__ A,
                                             const u16* __restrict__ B,
                                             void* __restrict__ Cout,
                                             const float* __restrict__ r1,
                                             const float* __restrict__ r2,
                                             int ldc, int mode, float scale,
                                             int bx, int by) {
    __shared__ __align__(16) u16 As[128 * 64];
    __shared__ __align__(16) u16 Bs[128 * 64];
    const int tid = threadIdx.x;
    const int l = tid & 63;
    const int wv = tid >> 6;
    const int wr = (wv >> 1) * 64, wc = (wv & 1) * 64;
    const int g = l >> 4, lo = l & 15;
    const size_t bm = (size_t)by * 128, bn = (size_t)bx * 128;
    const f32x4 fzero = {0.f, 0.f, 0.f, 0.f};

    f32x4 acc[4][4];
#pragma unroll
    for (int i = 0; i < 4; ++i)
#pragma unroll
        for (int j = 0; j < 4; ++j) acc[i][j] = fzero;

#define GSTAGE(KT)                                                                              \
    {                                                                                           \
        const int k0_ = (KT) * 64;                                                              \
        _Pragma("unroll") for (int q = 0; q < 4; ++q) {                                         \
            const int idx = q * 256 + tid;                                                      \
            const int row = idx >> 3, c8 = idx & 7;                                             \
            const int scol = (c8 ^ (row & 7)) * 8;                                              \
            const int dbase = q * 2048 + wv * 512;                                              \
            __builtin_amdgcn_global_load_lds((GU*)(A + (bm + row) * DIM + k0_ + scol),          \
                                             (LU*)&As[dbase], 16, 0, 0);                        \
            __builtin_amdgcn_global_load_lds((GU*)(B + (bn + row) * DIM + k0_ + scol),          \
                                             (LU*)&Bs[dbase], 16, 0, 0);                        \
        }                                                                                       \
    }

#define GCOMPUTE()                                                                              \
    {                                                                                           \
        _Pragma("unroll") for (int ks = 0; ks < 2; ++ks) {                                      \
            bf16x8 af[4], bfv[4];                                                               \
            _Pragma("unroll") for (int mi = 0; mi < 4; ++mi) {                                  \
                const int row = wr + mi * 16 + lo;                                              \
                const int sw = (ks * 4 + g) ^ (row & 7);                                        \
                af[mi] = *(const bf16x8*)(&As[row * 64 + sw * 8]);                              \
            }                                                                                   \
            _Pragma("unroll") for (int ni = 0; ni < 4; ++ni) {                                  \
                const int row = wc + ni * 16 + lo;                                              \
                const int sw = (ks * 4 + g) ^ (row & 7);                                        \
                bfv[ni] = *(const bf16x8*)(&Bs[row * 64 + sw * 8]);                             \
            }                                                                                   \
            _Pragma("unroll") for (int mi = 0; mi < 4; ++mi)                                    \
                _Pragma("unroll") for (int ni = 0; ni < 4; ++ni)                                \
                    acc[mi][ni] = __builtin_amdgcn_mfma_f32_16x16x32_bf16(af[mi], bfv[ni], acc[mi][ni], 0, 0, 0); \
        }                                                                                       \
    }

#pragma unroll 1
    for (int kt = 0; kt < 16; ++kt) {
        GSTAGE(kt)
        asm volatile("s_waitcnt vmcnt(0)" ::: "memory");
        __syncthreads();
        GCOMPUTE()
        __syncthreads();
    }
#undef GCOMPUTE
#undef GSTAGE

    if (mode == 0) {
        u16* C = (u16*)Cout;
#pragma unroll
        for (int mi = 0; mi < 4; ++mi)
#pragma unroll
            for (int ni = 0; ni < 4; ++ni)
#pragma unroll
                for (int r = 0; r < 4; ++r) {
                    size_t m = bm + wr + mi * 16 + g * 4 + r;
                    size_t n = bn + wc + ni * 16 + lo;
                    C[m * (size_t)ldc + n] = f2bf(acc[mi][ni][r] * scale);
                }
    } else if (mode == 2) {
        u16* C = (u16*)Cout;
#pragma unroll
        for (int mi = 0; mi < 4; ++mi)
#pragma unroll
            for (int ni = 0; ni < 4; ++ni)
#pragma unroll
                for (int r = 0; r < 4; ++r) {
                    size_t m = bm + wr + mi * 16 + g * 4 + r;
                    size_t n = bn + wc + ni * 16 + lo;
                    size_t o = (n >> 6) * ((size_t)NKPAD * 64) + m * 64 + (n & 63);
                    C[o] = f2bf(acc[mi][ni][r] * scale);
                }
    } else {
        float* C = (float*)Cout;
#pragma unroll
        for (int mi = 0; mi < 4; ++mi)
#pragma unroll
            for (int ni = 0; ni < 4; ++ni)
#pragma unroll
                for (int r = 0; r < 4; ++r) {
                    size_t m = bm + wr + mi * 16 + g * 4 + r;
                    size_t n = bn + wc + ni * 16 + lo;
                    size_t o = m * (size_t)ldc + n;
                    C[o] = acc[mi][ni][r] + r1[o] + r2[o];
                }
    }
}

// ---------- fused Q/K/V projections: [0,240) Q | [240,760) K | [760,1280) V ----------
__global__ __launch_bounds__(256, 3) void proj_kernel(const u16* __restrict__ qin,
                                                      const u16* __restrict__ kin,
                                                      const u16* __restrict__ WT,
                                                      u16* __restrict__ Qp,
                                                      u16* __restrict__ Kp,
                                                      u16* __restrict__ Vt) {
    const int b = blockIdx.x;
    if (b < 240) {
        gemm_bt_body(qin, WT, Qp, nullptr, nullptr, 1024, 0, 0.18033688f, b % 8, b / 8);
    } else if (b < 760) {
        const int bb = b - 240;
        gemm_bt_body(kin, WT + 1048576, Kp, nullptr, nullptr, 1024, 2, 1.0f, bb % 8, bb / 8);
    } else {
        const int bb = b - 760;
        gemm_bt_body(WT + 2097152, kin, Vt, nullptr, nullptr, NKPAD, 0, 1.0f, bb % 65, bb / 65);
    }
}

// ---------- out-projection ----------
__global__ __launch_bounds__(256, 3) void outproj_kernel(const u16* __restrict__ WTo,
                                                         const u16* __restrict__ ctx,
                                                         float* __restrict__ out,
                                                         const float* __restrict__ fc,
                                                         const float* __restrict__ ps) {
    gemm_bt_body(WTo, ctx, out, fc, ps, HW, 1, 1.0f, blockIdx.x, blockIdx.y);
}

// ---------- flash attention: 4 waves x 32 q-rows, LDS-shared K/V (KVB=64), dbuf ----------
// R10 version verbatim (measured 188-189 us, passed, 0 conflicts). Grid (NH, 30).
__global__ __launch_bounds__(256, 3) void attn_kernel(const u16* __restrict__ Q,
                                                      const u16* __restrict__ Kh,
                                                      const u16* __restrict__ Vt,
                                                      u16* __restrict__ ctx) {
    __shared__ __align__(16) u16 Kl[2][4096];
    __shared__ __align__(16) u16 Vl[2][4096];
    __shared__ float invl_s[4][32];
    const int h = blockIdx.x;                 // bid%8 = h%8 -> 2 heads per XCD L2
    const int tid = threadIdx.x;
    const int l = tid & 63, wv = tid >> 6;
    const int g = l >> 4, lo = l & 15;
    const int hoff = h * 64;
    const int qw = blockIdx.y * 128 + wv * 32;
    const f32x4 fzero = {0.f, 0.f, 0.f, 0.f};
    const int sig = (lo >> 2) * 8 + (lo & 3);

    const u16* Ksrc = Kh + (size_t)h * NKPAD * 64;
    const u16* Vsrc = Vt + (size_t)hoff * NKPAD;

    bf16x8 qa[2][2];
#pragma unroll
    for (int mi = 0; mi < 2; ++mi)
#pragma unroll
        for (int ks = 0; ks < 2; ++ks)
            qa[mi][ks] = *(const bf16x8*)(Q + (size_t)(qw + mi * 16 + lo) * DIM + hoff + ks * 32 + g * 8);

    f32x4 acc[2][4];
#pragma unroll
    for (int mi = 0; mi < 2; ++mi)
#pragma unroll
        for (int ni = 0; ni < 4; ++ni) acc[mi][ni] = fzero;
    float mrow[2] = {-1e30f, -1e30f};
    float lsum[2] = {0.f, 0.f};
    float pmax[2] = {-1e30f, -1e30f};

#define STAGE(BUF, IT)                                                                          \
    {                                                                                           \
        const int kks = (IT) * KVB;                                                             \
        _Pragma("unroll") for (int j = 0; j < 2; ++j) {                                         \
            const int inst = wv * 2 + j;                                                        \
            const int r_ = inst * 8 + (l >> 3);                                                 \
            const int c_ = l & 7;                                                               \
            const int hk_ = ((l >> 3) & 3) | ((inst & 1) << 2);                                 \
            const u16* gK = Ksrc + (size_t)(kks + r_) * 64 + ((c_ ^ hk_) * 8);                  \
            __builtin_amdgcn_global_load_lds((GU*)gK, (LU*)&Kl[BUF][inst * 512], 16, 0, 0);     \
            const u16* gV = Vsrc + (size_t)r_ * NKPAD + kks + ((c_ ^ (r_ & 7)) * 8);            \
            __builtin_amdgcn_global_load_lds((GU*)gV, (LU*)&Vl[BUF][inst * 512], 16, 0, 0);     \
        }                                                                                       \
    }

#define COMPUTE(BUF, NT, NS)                                                                    \
    {                                                                                           \
        f32x4 S[2][4];                                                                          \
        _Pragma("unroll") for (int kp = 0; kp < (NT) / 2; ++kp) {                               \
            bf16x8 kf[2][2];                                                                    \
            _Pragma("unroll") for (int k2 = 0; k2 < 2; ++k2)                                    \
                _Pragma("unroll") for (int ks = 0; ks < 2; ++ks) {                              \
                    const int kt = kp * 2 + k2;                                                 \
                    const int row = (kt >> 1) * 32 + (kt & 1) * 4 + sig;                        \
                    const int hk_ = (row & 3) | (((row >> 3) & 1) << 2);                        \
                    const int ck = (ks * 4 + g) ^ hk_;                                          \
                    kf[k2][ks] = *(const bf16x8*)(&Kl[BUF][row * 64 + ck * 8]);                 \
                }                                                                               \
            _Pragma("unroll") for (int mi = 0; mi < 2; ++mi)                                    \
                _Pragma("unroll") for (int k2 = 0; k2 < 2; ++k2) {                              \
                    f32x4 s_ = __builtin_amdgcn_mfma_f32_16x16x32_bf16(kf[k2][0], qa[mi][0], fzero, 0, 0, 0); \
                    S[mi][kp * 2 + k2] = __builtin_amdgcn_mfma_f32_16x16x32_bf16(kf[k2][1], qa[mi][1], s_, 0, 0, 0); \
                }                                                                               \
        }                                                                                       \
        _Pragma("unroll") for (int mi = 0; mi < 2; ++mi)                                        \
            _Pragma("unroll") for (int kt = 0; kt < (NT); ++kt) {                               \
                f32x4 sv = S[mi][kt];                                                           \
                pmax[mi] = fmaxf(pmax[mi], fmaxf(fmaxf(sv[0], sv[1]), fmaxf(sv[2], sv[3])));    \
            }                                                                                   \
        if (__any(fmaxf(pmax[0] - mrow[0], pmax[1] - mrow[1]) > THR)) {                         \
            _Pragma("unroll") for (int mi = 0; mi < 2; ++mi) {                                  \
                float v = pmax[mi];                                                             \
                v = fmaxf(v, __shfl_xor(v, 16));                                                \
                v = fmaxf(v, __shfl_xor(v, 32));                                                \
                float mn = fmaxf(mrow[mi], v);                                                  \
                float fct = exp2fast(mrow[mi] - mn);                                            \
                mrow[mi] = mn;                                                                  \
                lsum[mi] *= fct;                                                                \
                _Pragma("unroll") for (int r = 0; r < 4; ++r) {                                 \
                    float fr_ = __shfl(fct, g * 4 + r);                                         \
                    _Pragma("unroll") for (int ni = 0; ni < 4; ++ni) acc[mi][ni][r] *= fr_;     \
                }                                                                               \
            }                                                                                   \
        }                                                                                       \
        _Pragma("unroll") for (int s = 0; s < (NS); ++s) {                                      \
            bf16x8 vb[4];                                                                       \
            _Pragma("unroll") for (int ni = 0; ni < 4; ++ni) {                                  \
                const int row = ni * 16 + lo;                                                   \
                const int ck = (s * 4 + g) ^ (row & 7);                                         \
                vb[ni] = *(const bf16x8*)(&Vl[BUF][row * 64 + ck * 8]);                         \
            }                                                                                   \
            _Pragma("unroll") for (int mi = 0; mi < 2; ++mi) {                                  \
                float p0 = exp2fast(S[mi][2 * s][0] - mrow[mi]);                                \
                float p1 = exp2fast(S[mi][2 * s][1] - mrow[mi]);                                \
                float p2 = exp2fast(S[mi][2 * s][2] - mrow[mi]);                                \
                float p3 = exp2fast(S[mi][2 * s][3] - mrow[mi]);                                \
                float p4 = exp2fast(S[mi][2 * s + 1][0] - mrow[mi]);                            \
                float p5 = exp2fast(S[mi][2 * s + 1][1] - mrow[mi]);                            \
                float p6 = exp2fast(S[mi][2 * s + 1][2] - mrow[mi]);                            \
                float p7 = exp2fast(S[mi][2 * s + 1][3] - mrow[mi]);                            \
                lsum[mi] += ((p0 + p1) + (p2 + p3)) + ((p4 + p5) + (p6 + p7));                  \
                union { unsigned u[4]; bf16x8 v; } pu;                                          \
                asm("v_cvt_pk_bf16_f32 %0, %1, %2" : "=v"(pu.u[0]) : "v"(p0), "v"(p1));         \
                asm("v_cvt_pk_bf16_f32 %0, %1, %2" : "=v"(pu.u[1]) : "v"(p2), "v"(p3));         \
                asm("v_cvt_pk_bf16_f32 %0, %1, %2" : "=v"(pu.u[2]) : "v"(p4), "v"(p5));         \
                asm("v_cvt_pk_bf16_f32 %0, %1, %2" : "=v"(pu.u[3]) : "v"(p6), "v"(p7));         \
                _Pragma("unroll") for (int ni = 0; ni < 4; ++ni)                                \
                    acc[mi][ni] = __builtin_amdgcn_mfma_f32_16x16x32_bf16(pu.v, vb[ni], acc[mi][ni], 0, 0, 0); \
            }                                                                                   \
        }                                                                                       \
    }

    STAGE(0, 0)
    asm volatile("s_waitcnt vmcnt(0)" ::: "memory");
    __syncthreads();

#pragma unroll 1
    for (int it = 0; it < 128; it += 2) {
        STAGE(1, it + 1)
        COMPUTE(0, 4, 2)
        asm volatile("s_waitcnt vmcnt(0)" ::: "memory");
        __syncthreads();
        STAGE(0, it + 2)          // it=126 stages the tail window (keys 8192..8255)
        COMPUTE(1, 4, 2)
        asm volatile("s_waitcnt vmcnt(0)" ::: "memory");
        __syncthreads();
    }
    // tail: keys 8192..8223 (32 real keys; zero-padded rows never touched)
    COMPUTE(0, 2, 1)
#undef COMPUTE
#undef STAGE

    // row totals: sum l partials across the 4 g-lanes of each q-row
#pragma unroll
    for (int mi = 0; mi < 2; ++mi) {
        float t = lsum[mi];
        t += __shfl_xor(t, 16);
        t += __shfl_xor(t, 32);
        lsum[mi] = t;
    }
    // broadcast 1/l through per-wave LDS (acc rows are g*4+r, state rows are lo)
    if (l < 16) {
        invl_s[wv][lo] = 1.0f / lsum[0];
        invl_s[wv][16 + lo] = 1.0f / lsum[1];
    }
#pragma unroll
    for (int mi = 0; mi < 2; ++mi)
#pragma unroll
        for (int ni = 0; ni < 4; ++ni)
#pragma unroll
            for (int r = 0; r < 4; ++r) {
                float val = acc[mi][ni][r] * invl_s[wv][mi * 16 + g * 4 + r];
                ctx[(size_t)(qw + mi * 16 + g * 4 + r) * DIM + hoff + ni * 16 + lo] = f2bf(val);
            }
}

extern "C" void kernel_launch(void* const* d_in, const int* in_sizes, int n_in,
                              void* d_out, int out_size, void* d_ws, size_t ws_size,
                              hipStream_t stream) {
    const float* fc  = (const float*)d_in[0];
    const float* ps  = (const float*)d_in[1];
    const float* fr  = (const float*)d_in[2];
    const float* em  = (const float*)d_in[3];
    const float* gc  = (const float*)d_in[4];
    const float* Wq  = (const float*)d_in[5];
    const float* Wk  = (const float*)d_in[6];
    const float* Wv  = (const float*)d_in[7];
    const float* Wo  = (const float*)d_in[8];
    const int* sel   = (const int*)d_in[9];
    const int* midx  = (const int*)d_in[10];
    const int* gidx  = (const int*)d_in[11];

    char* w = (char*)d_ws;
    u16* WT  = (u16*)(w);                       //  8 MB: 4x [1024][1024] bf16
    u16* qin = (u16*)(w + 8388608ull);          //  7.5 MB [3840][1024]
    u16* kin = (u16*)(w + 16252928ull);         // 16.25 MB [8320][1024]
    u16* Qp  = (u16*)(w + 33292288ull);         //  7.5 MB [3840][1024]
    u16* Kp  = (u16*)(w + 41156608ull);         // 16.25 MB [16][8320][64] head-major
    u16* Vt  = (u16*)(w + 58195968ull);         // 16.25 MB [1024][8320]
    u16* ctx = (u16*)(w + 75235328ull);         //  7.5 MB [3840][1024]
    float* out = (float*)d_out;

    prep_kernel<<<dim3(12362), dim3(256), 0, stream>>>(Wq, Wk, Wv, Wo, fc, ps, fr, em, gc,
                                                       sel, midx, gidx, WT, qin, kin);
    proj_kernel<<<dim3(1280), dim3(256), 0, stream>>>(qin, kin, WT, Qp, Kp, Vt);

    attn_kernel<<<dim3(NH, 30), dim3(256), 0, stream>>>(Qp, Kp, Vt, ctx);

    outproj_kernel<<<dim3(30, 8), dim3(256), 0, stream>>>(WT + 3145728, ctx, out, fc, ps);
}